// Round 1
// baseline (1188.515 us; speedup 1.0000x reference)
//
#include <hip/hip_runtime.h>

#define NN 50000
#define EE 600000
#define CC 128
#define ECC 16
#define LL 4
#define NR 16
#define LN_EPS 1e-5f

// ---------------- CSR build ----------------

__global__ void count_kernel(const int* __restrict__ dst, int* __restrict__ counts, int E) {
  int e = blockIdx.x * blockDim.x + threadIdx.x;
  if (e < E) atomicAdd(&counts[dst[e]], 1);
}

__global__ __launch_bounds__(1024) void scan_kernel(const int* __restrict__ counts,
                                                    int* __restrict__ rowptr, int n) {
  __shared__ int buf[1024];
  __shared__ int carry_s;
  const int tid = threadIdx.x;
  if (tid == 0) { carry_s = 0; rowptr[0] = 0; }
  __syncthreads();
  for (int base = 0; base < n; base += 1024) {
    const int i = base + tid;
    int v = (i < n) ? counts[i] : 0;
    buf[tid] = v;
    __syncthreads();
    for (int off = 1; off < 1024; off <<= 1) {
      int t = (tid >= off) ? buf[tid - off] : 0;
      __syncthreads();
      buf[tid] += t;
      __syncthreads();
    }
    const int incl = buf[tid] + carry_s;
    if (i < n) rowptr[i + 1] = incl;
    __syncthreads();
    if (tid == 1023) carry_s = incl;
    __syncthreads();
  }
}

__global__ void fill_kernel(const int* __restrict__ src, const int* __restrict__ dst,
                            const int* __restrict__ rowptr, int* __restrict__ cursor,
                            int* __restrict__ eidx, int* __restrict__ esrc, int E) {
  int e = blockIdx.x * blockDim.x + threadIdx.x;
  if (e < E) {
    const int d = dst[e];
    const int pos = rowptr[d] + atomicAdd(&cursor[d], 1);
    eidx[pos] = e;
    esrc[pos] = src[e];
  }
}

// ---------------- fused GINE layer ----------------
// block = 256 threads (4 waves), NR=16 nodes per block. 50000 % 16 == 0 -> no tail.
// Phases: edge aggregation -> GEMM1+SiLU -> GEMM2+residual -> LayerNorm.

__global__ __launch_bounds__(256) void layer_kernel(
    const float* __restrict__ x_in, float* __restrict__ x_out,
    const float* __restrict__ edge_attr,
    const float* __restrict__ We, const float* __restrict__ be,
    const float* __restrict__ W1, const float* __restrict__ b1,
    const float* __restrict__ W2, const float* __restrict__ b2,
    const float* __restrict__ gamma, const float* __restrict__ beta,
    const int* __restrict__ rowptr, const int* __restrict__ eidx,
    const int* __restrict__ esrc)
{
  __shared__ float h_tile[NR][CC];   // h = x + agg ; later reused for y
  __shared__ float t_tile[NR][CC];   // silu(h@W1+b1)
  __shared__ float partial[2][CC];

  const int tid = threadIdx.x;
  const int c = tid & (CC - 1);      // channel 0..127
  const int half = tid >> 7;         // 0/1: which edge slot / which row group
  const int node0 = blockIdx.x * NR;

  // Per-thread We column (16 regs) + bias
  float wec[ECC];
  #pragma unroll
  for (int k = 0; k < ECC; ++k) wec[k] = We[k * CC + c];
  const float bev = be[c];

  // ---- Phase 1: aggregation.  agg[n][c] = sum_e relu(x[src][c] + silu(ea)) ----
  for (int r = 0; r < NR; ++r) {
    const int n = node0 + r;
    const int p0 = rowptr[n], p1 = rowptr[n + 1];
    float acc = 0.f;
    for (int p = p0 + half; p < p1; p += 2) {
      const int e = eidx[p];
      const int s = esrc[p];
      const float4* ar = (const float4*)(edge_attr + e * ECC);
      const float4 a0 = ar[0], a1 = ar[1], a2 = ar[2], a3 = ar[3];
      float ea = bev
        + a0.x*wec[0]  + a0.y*wec[1]  + a0.z*wec[2]  + a0.w*wec[3]
        + a1.x*wec[4]  + a1.y*wec[5]  + a1.z*wec[6]  + a1.w*wec[7]
        + a2.x*wec[8]  + a2.y*wec[9]  + a2.z*wec[10] + a2.w*wec[11]
        + a3.x*wec[12] + a3.y*wec[13] + a3.z*wec[14] + a3.w*wec[15];
      ea = ea / (1.f + __expf(-ea));              // SiLU
      const float m = x_in[s * CC + c] + ea;
      acc += fmaxf(m, 0.f);                        // ReLU + sum
    }
    partial[half][c] = acc;
    __syncthreads();
    if (half == 0) {
      h_tile[r][c] = x_in[n * CC + c] + partial[0][c] + partial[1][c];
    }
    __syncthreads();
  }

  // ---- Phase 2: t = silu(h @ W1 + b1) ----
  const int r0 = half * 8;
  {
    float acc1[8];
    const float bv = b1[c];
    #pragma unroll
    for (int r = 0; r < 8; ++r) acc1[r] = bv;
    #pragma unroll 4
    for (int k = 0; k < CC; ++k) {
      const float w = W1[k * CC + c];
      #pragma unroll
      for (int r = 0; r < 8; ++r) acc1[r] += h_tile[r0 + r][k] * w;
    }
    #pragma unroll
    for (int r = 0; r < 8; ++r) {
      const float v = acc1[r];
      t_tile[r0 + r][c] = v / (1.f + __expf(-v));
    }
  }
  __syncthreads();

  // ---- Phase 3: y = x + (t @ W2 + b2), stored back into h_tile ----
  {
    float acc2[8];
    const float bv = b2[c];
    #pragma unroll
    for (int r = 0; r < 8; ++r) acc2[r] = bv;
    #pragma unroll 4
    for (int k = 0; k < CC; ++k) {
      const float w = W2[k * CC + c];
      #pragma unroll
      for (int r = 0; r < 8; ++r) acc2[r] += t_tile[r0 + r][k] * w;
    }
    #pragma unroll
    for (int r = 0; r < 8; ++r) {
      h_tile[r0 + r][c] = acc2[r] + x_in[(node0 + r0 + r) * CC + c];
    }
  }
  __syncthreads();

  // ---- Phase 4: LayerNorm over channels, write x_out ----
  {
    const int rr = tid >> 4;        // row 0..15
    const int g = tid & 15;         // 16 threads per row, 8 channels each
    float v[8], s = 0.f, s2 = 0.f;
    #pragma unroll
    for (int j = 0; j < 8; ++j) {
      const float y = h_tile[rr][g * 8 + j];
      v[j] = y; s += y; s2 += y * y;
    }
    #pragma unroll
    for (int off = 1; off < 16; off <<= 1) {
      s  += __shfl_xor(s, off);
      s2 += __shfl_xor(s2, off);
    }
    const float mean = s * (1.f / 128.f);
    const float var = s2 * (1.f / 128.f) - mean * mean;
    const float rstd = rsqrtf(var + LN_EPS);
    float o[8];
    #pragma unroll
    for (int j = 0; j < 8; ++j) {
      const int ch = g * 8 + j;
      o[j] = (v[j] - mean) * rstd * gamma[ch] + beta[ch];
    }
    float4* outp = (float4*)(x_out + (node0 + rr) * CC + g * 8);
    outp[0] = make_float4(o[0], o[1], o[2], o[3]);
    outp[1] = make_float4(o[4], o[5], o[6], o[7]);
  }
}

// ---------------- launch ----------------

extern "C" void kernel_launch(void* const* d_in, const int* in_sizes, int n_in,
                              void* d_out, int out_size, void* d_ws, size_t ws_size,
                              hipStream_t stream) {
  const float* x         = (const float*)d_in[0];
  const float* edge_attr = (const float*)d_in[1];
  const float* We        = (const float*)d_in[2];
  const float* be        = (const float*)d_in[3];
  const float* W1        = (const float*)d_in[4];
  const float* b1        = (const float*)d_in[5];
  const float* W2        = (const float*)d_in[6];
  const float* b2        = (const float*)d_in[7];
  const float* gamma     = (const float*)d_in[8];
  const float* beta      = (const float*)d_in[9];
  const int*   ei        = (const int*)d_in[10];
  const int*   src       = ei;        // edge_index[0]
  const int*   dst       = ei + EE;   // edge_index[1]
  float* out = (float*)d_out;

  char* ws = (char*)d_ws;
  float* xbuf   = (float*)(ws);                 // 25,600,000 B
  int*   counts = (int*)(ws + 25600000);        //    200,000 B
  int*   rowptr = (int*)(ws + 25800000);        //    200,004 B
  int*   cursor = (int*)(ws + 26000128);        //    200,000 B
  int*   eidx   = (int*)(ws + 26200128);        //  2,400,000 B
  int*   esrc   = (int*)(ws + 28600128);        //  2,400,000 B
  // total ws use: 31,000,128 B

  hipMemsetAsync(counts, 0, (size_t)NN * 4, stream);
  hipMemsetAsync(cursor, 0, (size_t)NN * 4, stream);
  count_kernel<<<(EE + 255) / 256, 256, 0, stream>>>(dst, counts, EE);
  scan_kernel<<<1, 1024, 0, stream>>>(counts, rowptr, NN);
  fill_kernel<<<(EE + 255) / 256, 256, 0, stream>>>(src, dst, rowptr, cursor, eidx, esrc, EE);

  const float* xin = x;
  float* bufs[LL] = { xbuf, out, xbuf, out };
  for (int l = 0; l < LL; ++l) {
    float* xo = bufs[l];
    layer_kernel<<<NN / NR, 256, 0, stream>>>(
        xin, xo, edge_attr, We, be,
        W1 + (size_t)l * CC * CC, b1 + (size_t)l * CC,
        W2 + (size_t)l * CC * CC, b2 + (size_t)l * CC,
        gamma + (size_t)l * CC, beta + (size_t)l * CC,
        rowptr, eidx, esrc);
    xin = xo;
  }
}

// Round 2
// 796.486 us; speedup vs baseline: 1.4922x; 1.4922x over previous
//
#include <hip/hip_runtime.h>

#define NN 50000
#define EE 600000
#define CC 128
#define ECC 16
#define LL 4
#define LN_EPS 1e-5f
#define MTILE 80
#define PADC 136   // LDS row stride in bf16 elems: 136*2B = 17*16B -> 2-way (free) bank pattern

typedef float f32x4 __attribute__((ext_vector_type(4)));
typedef short bf16x8 __attribute__((ext_vector_type(8)));

static __device__ __forceinline__ float bf2f(unsigned short u) {
  union { unsigned int i; float f; } v; v.i = ((unsigned int)u) << 16; return v.f;
}
static __device__ __forceinline__ unsigned short f2bf(float f) {
  union { float f; unsigned int i; } v; v.f = f;
  unsigned int b = v.i + 0x7FFFu + ((v.i >> 16) & 1u);
  return (unsigned short)(b >> 16);
}
static __device__ __forceinline__ float silu_f(float v) {
  return v / (1.f + __expf(-v));
}

// ---------------- CSR build ----------------

__global__ void count_kernel(const int* __restrict__ dst, int* __restrict__ counts, int E) {
  int e = blockIdx.x * blockDim.x + threadIdx.x;
  if (e < E) atomicAdd(&counts[dst[e]], 1);
}

__global__ __launch_bounds__(1024) void scan_kernel(const int* __restrict__ counts,
                                                    int* __restrict__ rowptr, int n) {
  __shared__ int buf[1024];
  __shared__ int carry_s;
  const int tid = threadIdx.x;
  if (tid == 0) { carry_s = 0; rowptr[0] = 0; }
  __syncthreads();
  for (int base = 0; base < n; base += 1024) {
    const int i = base + tid;
    int v = (i < n) ? counts[i] : 0;
    buf[tid] = v;
    __syncthreads();
    for (int off = 1; off < 1024; off <<= 1) {
      int t = (tid >= off) ? buf[tid - off] : 0;
      __syncthreads();
      buf[tid] += t;
      __syncthreads();
    }
    const int incl = buf[tid] + carry_s;
    if (i < n) rowptr[i + 1] = incl;
    __syncthreads();
    if (tid == 1023) carry_s = incl;
    __syncthreads();
  }
}

__global__ void fill_kernel(const int* __restrict__ src, const int* __restrict__ dst,
                            const int* __restrict__ rowptr, int* __restrict__ cursor,
                            int* __restrict__ eidx, int* __restrict__ esrc, int E) {
  int e = blockIdx.x * blockDim.x + threadIdx.x;
  if (e < E) {
    const int d = dst[e];
    const int pos = rowptr[d] + atomicAdd(&cursor[d], 1);
    eidx[pos] = e;
    esrc[pos] = src[e];
  }
}

// ---------------- ea precompute (CSR order, bf16) ----------------
// ea_csr[p][c] = silu(edge_attr[eidx[p]] @ We + be)[c], shared across all 4 layers.

__global__ __launch_bounds__(256) void ea_kernel(const float* __restrict__ edge_attr,
                                                 const float* __restrict__ We,
                                                 const float* __restrict__ be,
                                                 const int* __restrict__ eidx,
                                                 unsigned short* __restrict__ ea) {
  const int tid = threadIdx.x;
  const int c = tid & (CC - 1);
  const int g = tid >> 7;
  float wec[ECC];
  #pragma unroll
  for (int k = 0; k < ECC; ++k) wec[k] = We[k * CC + c];
  const float bev = be[c];
  const int base = blockIdx.x * 16 + g * 8;
  #pragma unroll
  for (int i = 0; i < 8; ++i) {
    const int p = base + i;
    if (p >= EE) return;
    const int e = eidx[p];
    const float4* ar = (const float4*)(edge_attr + (size_t)e * ECC);
    const float4 a0 = ar[0], a1 = ar[1], a2 = ar[2], a3 = ar[3];
    float v = bev
      + a0.x*wec[0]  + a0.y*wec[1]  + a0.z*wec[2]  + a0.w*wec[3]
      + a1.x*wec[4]  + a1.y*wec[5]  + a1.z*wec[6]  + a1.w*wec[7]
      + a2.x*wec[8]  + a2.y*wec[9]  + a2.z*wec[10] + a2.w*wec[11]
      + a3.x*wec[12] + a3.y*wec[13] + a3.z*wec[14] + a3.w*wec[15];
    ea[(size_t)p * CC + c] = f2bf(silu_f(v));
  }
}

// ---------------- weight transpose+cast: wt[l][mat][c][k] = bf16(W[l][k][c]) ----------------

__global__ __launch_bounds__(128) void wconv_kernel(const float* __restrict__ W1,
                                                    const float* __restrict__ W2,
                                                    unsigned short* __restrict__ wt) {
  const int b = blockIdx.x;
  const int c = b & (CC - 1);
  const int mat = (b >> 7) & 1;
  const int l = b >> 8;
  const float* W = (mat ? W2 : W1) + (size_t)l * CC * CC;
  unsigned short* o = wt + ((size_t)l * 2 + mat) * CC * CC + (size_t)c * CC;
  const int k = threadIdx.x;
  o[k] = f2bf(W[(size_t)k * CC + c]);
}

// ---------------- aggregation: h[n] = bf16( x[n] + sum_e relu(x[src]+ea[e]) ) ----------------
// One 128-thread group per node, no barriers, edges unrolled x2.
// MODE 0: read precomputed bf16 ea (CSR-ordered).  MODE 1: recompute ea on the fly.

template <int MODE>
__global__ __launch_bounds__(256) void agg_kernel(const float* __restrict__ x_in,
                                                  unsigned short* __restrict__ h_out,
                                                  const unsigned short* __restrict__ ea,
                                                  const float* __restrict__ edge_attr,
                                                  const float* __restrict__ We,
                                                  const float* __restrict__ be,
                                                  const int* __restrict__ rowptr,
                                                  const int* __restrict__ eidx,
                                                  const int* __restrict__ esrc) {
  const int tid = threadIdx.x;
  const int c = tid & (CC - 1);
  const int g = tid >> 7;
  const int n = blockIdx.x * 2 + g;

  float wec[ECC];
  float bev = 0.f;
  if (MODE == 1) {
    #pragma unroll
    for (int k = 0; k < ECC; ++k) wec[k] = We[k * CC + c];
    bev = be[c];
  }

  const int p0 = rowptr[n], p1 = rowptr[n + 1];
  float acc = 0.f;
  int p = p0;
  for (; p + 2 <= p1; p += 2) {
    const int s0 = esrc[p], s1 = esrc[p + 1];
    float m0, m1;
    if (MODE == 0) {
      m0 = bf2f(ea[(size_t)p * CC + c]);
      m1 = bf2f(ea[(size_t)(p + 1) * CC + c]);
    } else {
      const int e0 = eidx[p], e1 = eidx[p + 1];
      const float4* ar0 = (const float4*)(edge_attr + (size_t)e0 * ECC);
      const float4* ar1 = (const float4*)(edge_attr + (size_t)e1 * ECC);
      const float4 a0 = ar0[0], a1 = ar0[1], a2 = ar0[2], a3 = ar0[3];
      const float4 b0 = ar1[0], b1 = ar1[1], b2 = ar1[2], b3 = ar1[3];
      float v0 = bev
        + a0.x*wec[0]  + a0.y*wec[1]  + a0.z*wec[2]  + a0.w*wec[3]
        + a1.x*wec[4]  + a1.y*wec[5]  + a1.z*wec[6]  + a1.w*wec[7]
        + a2.x*wec[8]  + a2.y*wec[9]  + a2.z*wec[10] + a2.w*wec[11]
        + a3.x*wec[12] + a3.y*wec[13] + a3.z*wec[14] + a3.w*wec[15];
      float v1 = bev
        + b0.x*wec[0]  + b0.y*wec[1]  + b0.z*wec[2]  + b0.w*wec[3]
        + b1.x*wec[4]  + b1.y*wec[5]  + b1.z*wec[6]  + b1.w*wec[7]
        + b2.x*wec[8]  + b2.y*wec[9]  + b2.z*wec[10] + b2.w*wec[11]
        + b3.x*wec[12] + b3.y*wec[13] + b3.z*wec[14] + b3.w*wec[15];
      m0 = silu_f(v0);
      m1 = silu_f(v1);
    }
    const float x0 = x_in[(size_t)s0 * CC + c];
    const float x1 = x_in[(size_t)s1 * CC + c];
    acc += fmaxf(x0 + m0, 0.f) + fmaxf(x1 + m1, 0.f);
  }
  if (p < p1) {
    const int s0 = esrc[p];
    float m0;
    if (MODE == 0) {
      m0 = bf2f(ea[(size_t)p * CC + c]);
    } else {
      const int e0 = eidx[p];
      const float4* ar0 = (const float4*)(edge_attr + (size_t)e0 * ECC);
      const float4 a0 = ar0[0], a1 = ar0[1], a2 = ar0[2], a3 = ar0[3];
      float v0 = bev
        + a0.x*wec[0]  + a0.y*wec[1]  + a0.z*wec[2]  + a0.w*wec[3]
        + a1.x*wec[4]  + a1.y*wec[5]  + a1.z*wec[6]  + a1.w*wec[7]
        + a2.x*wec[8]  + a2.y*wec[9]  + a2.z*wec[10] + a2.w*wec[11]
        + a3.x*wec[12] + a3.y*wec[13] + a3.z*wec[14] + a3.w*wec[15];
      m0 = silu_f(v0);
    }
    acc += fmaxf(x_in[(size_t)s0 * CC + c] + m0, 0.f);
  }
  h_out[(size_t)n * CC + c] = f2bf(x_in[(size_t)n * CC + c] + acc);
}

// ---------------- fused MLP + residual + LayerNorm (MFMA bf16) ----------------
// Block: 256 threads (4 waves), MTILE=80 nodes. Wave w owns output cols [32w, 32w+32).

__global__ __launch_bounds__(256) void mlp_kernel(const float* __restrict__ x_in,
                                                  const unsigned short* __restrict__ hbuf,
                                                  const unsigned short* __restrict__ wt1,
                                                  const unsigned short* __restrict__ wt2,
                                                  const float* __restrict__ b1,
                                                  const float* __restrict__ b2,
                                                  const float* __restrict__ gamma,
                                                  const float* __restrict__ beta,
                                                  float* __restrict__ x_out) {
  __shared__ unsigned short hA[MTILE * PADC];
  __shared__ unsigned short tA[MTILE * PADC];
  __shared__ float red[MTILE][4][2];

  const int tid = threadIdx.x;
  const int lane = tid & 63;
  const int wv = tid >> 6;
  const int node0 = blockIdx.x * MTILE;
  const int colq = lane & 15;   // col within 16-tile
  const int krow = lane >> 4;   // 0..3
  const int colb = wv * 32;

  // stage h tile (bf16, 16B per thread-chunk)
  for (int idx = tid; idx < MTILE * 16; idx += 256) {
    const int row = idx >> 4, ch = idx & 15;
    *(uint4*)(&hA[row * PADC + ch * 8]) =
        *(const uint4*)(hbuf + (size_t)(node0 + row) * CC + ch * 8);
  }
  __syncthreads();

  // ---- GEMM1: t = silu(h @ W1 + b1) ----
  bf16x8 bw[2][4];
  #pragma unroll
  for (int n2 = 0; n2 < 2; ++n2)
    #pragma unroll
    for (int kk = 0; kk < 4; ++kk)
      bw[n2][kk] = *(const bf16x8*)(wt1 + (size_t)(colb + n2 * 16 + colq) * CC + kk * 32 + krow * 8);

  f32x4 acc[5][2];
  #pragma unroll
  for (int m = 0; m < 5; ++m) { acc[m][0] = (f32x4)0.f; acc[m][1] = (f32x4)0.f; }

  #pragma unroll
  for (int m = 0; m < 5; ++m)
    #pragma unroll
    for (int kk = 0; kk < 4; ++kk) {
      const bf16x8 a = *(const bf16x8*)(&hA[(m * 16 + colq) * PADC + kk * 32 + krow * 8]);
      acc[m][0] = __builtin_amdgcn_mfma_f32_16x16x32_bf16(a, bw[0][kk], acc[m][0], 0, 0, 0);
      acc[m][1] = __builtin_amdgcn_mfma_f32_16x16x32_bf16(a, bw[1][kk], acc[m][1], 0, 0, 0);
    }

  const float b1v0 = b1[colb + colq], b1v1 = b1[colb + 16 + colq];
  #pragma unroll
  for (int m = 0; m < 5; ++m)
    #pragma unroll
    for (int r = 0; r < 4; ++r) {
      const int row = m * 16 + krow * 4 + r;
      tA[row * PADC + colb + colq]      = f2bf(silu_f(acc[m][0][r] + b1v0));
      tA[row * PADC + colb + 16 + colq] = f2bf(silu_f(acc[m][1][r] + b1v1));
    }
  __syncthreads();

  // ---- GEMM2: y = x + t @ W2 + b2 ----
  #pragma unroll
  for (int n2 = 0; n2 < 2; ++n2)
    #pragma unroll
    for (int kk = 0; kk < 4; ++kk)
      bw[n2][kk] = *(const bf16x8*)(wt2 + (size_t)(colb + n2 * 16 + colq) * CC + kk * 32 + krow * 8);

  f32x4 acc2[5][2];
  #pragma unroll
  for (int m = 0; m < 5; ++m) { acc2[m][0] = (f32x4)0.f; acc2[m][1] = (f32x4)0.f; }

  #pragma unroll
  for (int m = 0; m < 5; ++m)
    #pragma unroll
    for (int kk = 0; kk < 4; ++kk) {
      const bf16x8 a = *(const bf16x8*)(&tA[(m * 16 + colq) * PADC + kk * 32 + krow * 8]);
      acc2[m][0] = __builtin_amdgcn_mfma_f32_16x16x32_bf16(a, bw[0][kk], acc2[m][0], 0, 0, 0);
      acc2[m][1] = __builtin_amdgcn_mfma_f32_16x16x32_bf16(a, bw[1][kk], acc2[m][1], 0, 0, 0);
    }

  const float b2v0 = b2[colb + colq], b2v1 = b2[colb + 16 + colq];
  float yv[5][2][4];
  #pragma unroll
  for (int m = 0; m < 5; ++m)
    #pragma unroll
    for (int r = 0; r < 4; ++r) {
      const int row = m * 16 + krow * 4 + r;
      yv[m][0][r] = acc2[m][0][r] + b2v0 + x_in[(size_t)(node0 + row) * CC + colb + colq];
      yv[m][1][r] = acc2[m][1][r] + b2v1 + x_in[(size_t)(node0 + row) * CC + colb + 16 + colq];
    }

  // ---- LayerNorm: per-row stats across 4 waves ----
  #pragma unroll
  for (int m = 0; m < 5; ++m)
    #pragma unroll
    for (int r = 0; r < 4; ++r) {
      float s = yv[m][0][r] + yv[m][1][r];
      float s2 = yv[m][0][r] * yv[m][0][r] + yv[m][1][r] * yv[m][1][r];
      #pragma unroll
      for (int off = 1; off < 16; off <<= 1) {
        s  += __shfl_xor(s, off);
        s2 += __shfl_xor(s2, off);
      }
      if (colq == 0) {
        const int row = m * 16 + krow * 4 + r;
        red[row][wv][0] = s;
        red[row][wv][1] = s2;
      }
    }
  __syncthreads();

  const float gm0 = gamma[colb + colq], gm1 = gamma[colb + 16 + colq];
  const float bt0 = beta[colb + colq],  bt1 = beta[colb + 16 + colq];
  #pragma unroll
  for (int m = 0; m < 5; ++m)
    #pragma unroll
    for (int r = 0; r < 4; ++r) {
      const int row = m * 16 + krow * 4 + r;
      const float s  = red[row][0][0] + red[row][1][0] + red[row][2][0] + red[row][3][0];
      const float s2 = red[row][0][1] + red[row][1][1] + red[row][2][1] + red[row][3][1];
      const float mean = s * (1.f / 128.f);
      const float var = s2 * (1.f / 128.f) - mean * mean;
      const float rstd = rsqrtf(var + LN_EPS);
      float* op = x_out + (size_t)(node0 + row) * CC + colb;
      op[colq]      = (yv[m][0][r] - mean) * rstd * gm0 + bt0;
      op[16 + colq] = (yv[m][1][r] - mean) * rstd * gm1 + bt1;
    }
}

// ---------------- launch ----------------

extern "C" void kernel_launch(void* const* d_in, const int* in_sizes, int n_in,
                              void* d_out, int out_size, void* d_ws, size_t ws_size,
                              hipStream_t stream) {
  const float* x         = (const float*)d_in[0];
  const float* edge_attr = (const float*)d_in[1];
  const float* We        = (const float*)d_in[2];
  const float* be        = (const float*)d_in[3];
  const float* W1        = (const float*)d_in[4];
  const float* b1        = (const float*)d_in[5];
  const float* W2        = (const float*)d_in[6];
  const float* b2        = (const float*)d_in[7];
  const float* gamma     = (const float*)d_in[8];
  const float* beta      = (const float*)d_in[9];
  const int*   ei        = (const int*)d_in[10];
  const int*   src       = ei;        // edge_index[0]
  const int*   dst       = ei + EE;   // edge_index[1]
  float* out = (float*)d_out;

  char* ws = (char*)d_ws;
  float*          xbuf   = (float*)(ws + 0);                    // 25,600,000
  unsigned short* hbuf   = (unsigned short*)(ws + 25600000);    // 12,800,000 -> 38,400,000
  unsigned short* wt     = (unsigned short*)(ws + 38400000);    //    262,144 -> 38,662,144
  int*            counts = (int*)(ws + 38662400);               //    200,000 -> 38,862,400
  int*            rowptr = (int*)(ws + 38862592);               //    200,004 -> 39,062,596
  int*            cursor = (int*)(ws + 39062784);               //    200,000 -> 39,262,784
  int*            eidx   = (int*)(ws + 39262976);               //  2,400,000 -> 41,662,976
  int*            esrc   = (int*)(ws + 41663232);               //  2,400,000 -> 44,063,232
  unsigned short* ea     = (unsigned short*)(ws + 44063232);    // 153,600,000 -> 197,663,232
  const bool use_ea = (ws_size >= 197663232ull);

  hipMemsetAsync(counts, 0, (size_t)NN * 4, stream);
  hipMemsetAsync(cursor, 0, (size_t)NN * 4, stream);
  count_kernel<<<(EE + 255) / 256, 256, 0, stream>>>(dst, counts, EE);
  scan_kernel<<<1, 1024, 0, stream>>>(counts, rowptr, NN);
  fill_kernel<<<(EE + 255) / 256, 256, 0, stream>>>(src, dst, rowptr, cursor, eidx, esrc, EE);
  wconv_kernel<<<LL * 2 * CC, 128, 0, stream>>>(W1, W2, wt);
  if (use_ea)
    ea_kernel<<<EE / 16, 256, 0, stream>>>(edge_attr, We, be, eidx, ea);

  const float* xin = x;
  float* bufs[LL] = { xbuf, out, xbuf, out };
  for (int l = 0; l < LL; ++l) {
    float* xo = bufs[l];
    if (use_ea)
      agg_kernel<0><<<NN / 2, 256, 0, stream>>>(xin, hbuf, ea, edge_attr, We, be, rowptr, eidx, esrc);
    else
      agg_kernel<1><<<NN / 2, 256, 0, stream>>>(xin, hbuf, ea, edge_attr, We, be, rowptr, eidx, esrc);
    mlp_kernel<<<NN / MTILE, 256, 0, stream>>>(
        xin, hbuf,
        wt + ((size_t)l * 2) * CC * CC, wt + ((size_t)l * 2 + 1) * CC * CC,
        b1 + (size_t)l * CC, b2 + (size_t)l * CC,
        gamma + (size_t)l * CC, beta + (size_t)l * CC, xo);
    xin = xo;
  }
}

// Round 3
// 676.791 us; speedup vs baseline: 1.7561x; 1.1769x over previous
//
#include <hip/hip_runtime.h>

#define NN 50000
#define EE 600000
#define CC 128
#define ECC 16
#define LL 4
#define LN_EPS 1e-5f
#define MTILE 80
#define PADC 136   // LDS row stride in bf16 elems: 136*2B = 17*16B -> 2-way (free) bank pattern

typedef float f32x4 __attribute__((ext_vector_type(4)));
typedef short bf16x8 __attribute__((ext_vector_type(8)));

static __device__ __forceinline__ float bf2f(unsigned short u) {
  union { unsigned int i; float f; } v; v.i = ((unsigned int)u) << 16; return v.f;
}
static __device__ __forceinline__ unsigned short f2bf(float f) {
  union { float f; unsigned int i; } v; v.f = f;
  unsigned int b = v.i + 0x7FFFu + ((v.i >> 16) & 1u);
  return (unsigned short)(b >> 16);
}
static __device__ __forceinline__ float silu_f(float v) {
  return v / (1.f + __expf(-v));
}

// ---------------- CSR build ----------------

__global__ void count_kernel(const int* __restrict__ dst, int* __restrict__ counts, int E) {
  int e = blockIdx.x * blockDim.x + threadIdx.x;
  if (e < E) atomicAdd(&counts[dst[e]], 1);
}

// single-block chunked scan: thread-serial sums -> wave shfl scan -> cross-wave scan.
__global__ __launch_bounds__(1024) void scan_kernel(const int* __restrict__ counts,
                                                    int* __restrict__ rowptr, int n) {
  __shared__ int wsum[16];
  const int tid = threadIdx.x;
  const int lane = tid & 63, wv = tid >> 6;
  const int CH = (n + 1023) >> 10;   // 49
  const int i0 = tid * CH;
  int s = 0;
  for (int j = 0; j < CH; ++j) {
    const int i = i0 + j;
    if (i < n) s += counts[i];
  }
  int incl = s;
  #pragma unroll
  for (int off = 1; off < 64; off <<= 1) {
    int t = __shfl_up(incl, off);
    if (lane >= off) incl += t;
  }
  if (lane == 63) wsum[wv] = incl;
  __syncthreads();
  if (wv == 0) {
    int v = (lane < 16) ? wsum[lane] : 0;
    int vi = v;
    #pragma unroll
    for (int off = 1; off < 16; off <<= 1) {
      int t = __shfl_up(vi, off);
      if (lane >= off) vi += t;
    }
    if (lane < 16) wsum[lane] = vi - v;   // exclusive wave prefix
  }
  __syncthreads();
  int run = wsum[wv] + (incl - s);        // exclusive prefix before i0
  if (tid == 0) rowptr[0] = 0;
  for (int j = 0; j < CH; ++j) {
    const int i = i0 + j;
    if (i < n) { run += counts[i]; rowptr[i + 1] = run; }
  }
}

__global__ void fill_kernel(const int* __restrict__ src, const int* __restrict__ dst,
                            const int* __restrict__ rowptr, int* __restrict__ cursor,
                            int* __restrict__ eidx, int* __restrict__ esrc, int E) {
  int e = blockIdx.x * blockDim.x + threadIdx.x;
  if (e < E) {
    const int d = dst[e];
    const int pos = rowptr[d] + atomicAdd(&cursor[d], 1);
    eidx[pos] = e;
    esrc[pos] = src[e];
  }
}

// ---------------- We B-fragment prep (bf16, MFMA fragment order) ----------------
// webf[cg*512 + l*8 + j] = (k<16 ? bf16(We[k][cg*16+(l&15)]) : 0), k=(l>>4)*8+j

__global__ void webconv_kernel(const float* __restrict__ We, unsigned short* __restrict__ webf) {
  const int t = blockIdx.x * blockDim.x + threadIdx.x;
  if (t >= 8 * 64 * 8) return;
  const int j = t & 7, l = (t >> 3) & 63, cg = t >> 9;
  const int k = (l >> 4) * 8 + j, c = cg * 16 + (l & 15);
  webf[t] = (k < 16) ? f2bf(We[k * CC + c]) : (unsigned short)0;
}

// ---------------- ea precompute via MFMA (CSR order, bf16) ----------------
// Block: 256 threads / 4 waves, 64 CSR positions. Wave w: rows w*16..w*16+15.

__global__ __launch_bounds__(256) void ea_kernel(const float* __restrict__ edge_attr,
                                                 const unsigned short* __restrict__ webf,
                                                 const float* __restrict__ be,
                                                 const int* __restrict__ eidx,
                                                 unsigned short* __restrict__ ea) {
  __shared__ float er[64][20];   // pad 20: 16B-aligned float4 rows, <=2-way banks
  const int tid = threadIdx.x;
  const int lane = tid & 63, wv = tid >> 6;

  bf16x8 bw[8];
  #pragma unroll
  for (int cg = 0; cg < 8; ++cg)
    bw[cg] = *(const bf16x8*)(webf + cg * 512 + lane * 8);
  float bev[8];
  #pragma unroll
  for (int cg = 0; cg < 8; ++cg) bev[cg] = be[cg * 16 + (lane & 15)];

  const int base = blockIdx.x * 64;
  {
    const int r = tid >> 2, q = tid & 3;
    const int e = eidx[base + r];
    *(float4*)(&er[r][q * 4]) = *(const float4*)(edge_attr + (size_t)e * ECC + q * 4);
  }
  __syncthreads();

  // A-fragment: row = lane&15 (edge), k-octet = lane>>4; k>=16 -> zero pad
  const int arow = wv * 16 + (lane & 15);
  const int ko = lane >> 4;
  union { unsigned short u[8]; bf16x8 v; } afu;
  if (ko < 2) {
    #pragma unroll
    for (int j = 0; j < 8; ++j) afu.u[j] = f2bf(er[arow][ko * 8 + j]);
  } else {
    #pragma unroll
    for (int j = 0; j < 8; ++j) afu.u[j] = 0;
  }

  f32x4 acc[8];
  #pragma unroll
  for (int cg = 0; cg < 8; ++cg) {
    acc[cg] = (f32x4)0.f;
    acc[cg] = __builtin_amdgcn_mfma_f32_16x16x32_bf16(afu.v, bw[cg], acc[cg], 0, 0, 0);
  }

  // epilogue: C row = (lane>>4)*4+r (edge), col = cg*16 + (lane&15)
  const int row0 = base + wv * 16 + ko * 4;
  const int cb = lane & 15;
  #pragma unroll
  for (int cg = 0; cg < 8; ++cg)
    #pragma unroll
    for (int r = 0; r < 4; ++r) {
      const float v = acc[cg][r] + bev[cg];
      ea[(size_t)(row0 + r) * CC + cg * 16 + cb] = f2bf(silu_f(v));
    }
}

// ---------------- weight transpose+cast: wt[l][mat][c][k] = bf16(W[l][k][c]) ----------------

__global__ __launch_bounds__(128) void wconv_kernel(const float* __restrict__ W1,
                                                    const float* __restrict__ W2,
                                                    unsigned short* __restrict__ wt) {
  const int b = blockIdx.x;
  const int c = b & (CC - 1);
  const int mat = (b >> 7) & 1;
  const int l = b >> 8;
  const float* W = (mat ? W2 : W1) + (size_t)l * CC * CC;
  unsigned short* o = wt + ((size_t)l * 2 + mat) * CC * CC + (size_t)c * CC;
  const int k = threadIdx.x;
  o[k] = f2bf(W[(size_t)k * CC + c]);
}

// ---------------- aggregation: h[n] = bf16( x[n] + sum_e relu(x[src]+ea[e]) ) ----------------
// One 128-thread group per node, no barriers, edges unrolled x2.
// MODE 0: read precomputed bf16 ea (CSR-ordered).  MODE 1: recompute ea on the fly.

template <int MODE>
__global__ __launch_bounds__(256) void agg_kernel(const float* __restrict__ x_in,
                                                  unsigned short* __restrict__ h_out,
                                                  const unsigned short* __restrict__ ea,
                                                  const float* __restrict__ edge_attr,
                                                  const float* __restrict__ We,
                                                  const float* __restrict__ be,
                                                  const int* __restrict__ rowptr,
                                                  const int* __restrict__ eidx,
                                                  const int* __restrict__ esrc) {
  const int tid = threadIdx.x;
  const int c = tid & (CC - 1);
  const int g = tid >> 7;
  const int n = blockIdx.x * 2 + g;

  float wec[ECC];
  float bev = 0.f;
  if (MODE == 1) {
    #pragma unroll
    for (int k = 0; k < ECC; ++k) wec[k] = We[k * CC + c];
    bev = be[c];
  }

  const int p0 = rowptr[n], p1 = rowptr[n + 1];
  float acc = 0.f;
  int p = p0;
  for (; p + 2 <= p1; p += 2) {
    const int s0 = esrc[p], s1 = esrc[p + 1];
    float m0, m1;
    if (MODE == 0) {
      m0 = bf2f(ea[(size_t)p * CC + c]);
      m1 = bf2f(ea[(size_t)(p + 1) * CC + c]);
    } else {
      const int e0 = eidx[p], e1 = eidx[p + 1];
      const float4* ar0 = (const float4*)(edge_attr + (size_t)e0 * ECC);
      const float4* ar1 = (const float4*)(edge_attr + (size_t)e1 * ECC);
      const float4 a0 = ar0[0], a1 = ar0[1], a2 = ar0[2], a3 = ar0[3];
      const float4 b0 = ar1[0], b1 = ar1[1], b2 = ar1[2], b3 = ar1[3];
      float v0 = bev
        + a0.x*wec[0]  + a0.y*wec[1]  + a0.z*wec[2]  + a0.w*wec[3]
        + a1.x*wec[4]  + a1.y*wec[5]  + a1.z*wec[6]  + a1.w*wec[7]
        + a2.x*wec[8]  + a2.y*wec[9]  + a2.z*wec[10] + a2.w*wec[11]
        + a3.x*wec[12] + a3.y*wec[13] + a3.z*wec[14] + a3.w*wec[15];
      float v1 = bev
        + b0.x*wec[0]  + b0.y*wec[1]  + b0.z*wec[2]  + b0.w*wec[3]
        + b1.x*wec[4]  + b1.y*wec[5]  + b1.z*wec[6]  + b1.w*wec[7]
        + b2.x*wec[8]  + b2.y*wec[9]  + b2.z*wec[10] + b2.w*wec[11]
        + b3.x*wec[12] + b3.y*wec[13] + b3.z*wec[14] + b3.w*wec[15];
      m0 = silu_f(v0);
      m1 = silu_f(v1);
    }
    const float x0 = x_in[(size_t)s0 * CC + c];
    const float x1 = x_in[(size_t)s1 * CC + c];
    acc += fmaxf(x0 + m0, 0.f) + fmaxf(x1 + m1, 0.f);
  }
  if (p < p1) {
    const int s0 = esrc[p];
    float m0;
    if (MODE == 0) {
      m0 = bf2f(ea[(size_t)p * CC + c]);
    } else {
      const int e0 = eidx[p];
      const float4* ar0 = (const float4*)(edge_attr + (size_t)e0 * ECC);
      const float4 a0 = ar0[0], a1 = ar0[1], a2 = ar0[2], a3 = ar0[3];
      float v0 = bev
        + a0.x*wec[0]  + a0.y*wec[1]  + a0.z*wec[2]  + a0.w*wec[3]
        + a1.x*wec[4]  + a1.y*wec[5]  + a1.z*wec[6]  + a1.w*wec[7]
        + a2.x*wec[8]  + a2.y*wec[9]  + a2.z*wec[10] + a2.w*wec[11]
        + a3.x*wec[12] + a3.y*wec[13] + a3.z*wec[14] + a3.w*wec[15];
      m0 = silu_f(v0);
    }
    acc += fmaxf(x_in[(size_t)s0 * CC + c] + m0, 0.f);
  }
  h_out[(size_t)n * CC + c] = f2bf(x_in[(size_t)n * CC + c] + acc);
}

// ---------------- fused MLP + residual + LayerNorm (MFMA bf16) ----------------
// Block: 256 threads (4 waves), MTILE=80 nodes. Wave w owns output cols [32w, 32w+32).

__global__ __launch_bounds__(256) void mlp_kernel(const float* __restrict__ x_in,
                                                  const unsigned short* __restrict__ hbuf,
                                                  const unsigned short* __restrict__ wt1,
                                                  const unsigned short* __restrict__ wt2,
                                                  const float* __restrict__ b1,
                                                  const float* __restrict__ b2,
                                                  const float* __restrict__ gamma,
                                                  const float* __restrict__ beta,
                                                  float* __restrict__ x_out) {
  __shared__ unsigned short hA[MTILE * PADC];
  __shared__ unsigned short tA[MTILE * PADC];
  __shared__ float red[MTILE][4][2];

  const int tid = threadIdx.x;
  const int lane = tid & 63;
  const int wv = tid >> 6;
  const int node0 = blockIdx.x * MTILE;
  const int colq = lane & 15;   // col within 16-tile
  const int krow = lane >> 4;   // 0..3
  const int colb = wv * 32;

  // stage h tile (bf16, 16B per thread-chunk)
  for (int idx = tid; idx < MTILE * 16; idx += 256) {
    const int row = idx >> 4, ch = idx & 15;
    *(uint4*)(&hA[row * PADC + ch * 8]) =
        *(const uint4*)(hbuf + (size_t)(node0 + row) * CC + ch * 8);
  }
  __syncthreads();

  // ---- GEMM1: t = silu(h @ W1 + b1) ----
  bf16x8 bw[2][4];
  #pragma unroll
  for (int n2 = 0; n2 < 2; ++n2)
    #pragma unroll
    for (int kk = 0; kk < 4; ++kk)
      bw[n2][kk] = *(const bf16x8*)(wt1 + (size_t)(colb + n2 * 16 + colq) * CC + kk * 32 + krow * 8);

  f32x4 acc[5][2];
  #pragma unroll
  for (int m = 0; m < 5; ++m) { acc[m][0] = (f32x4)0.f; acc[m][1] = (f32x4)0.f; }

  #pragma unroll
  for (int m = 0; m < 5; ++m)
    #pragma unroll
    for (int kk = 0; kk < 4; ++kk) {
      const bf16x8 a = *(const bf16x8*)(&hA[(m * 16 + colq) * PADC + kk * 32 + krow * 8]);
      acc[m][0] = __builtin_amdgcn_mfma_f32_16x16x32_bf16(a, bw[0][kk], acc[m][0], 0, 0, 0);
      acc[m][1] = __builtin_amdgcn_mfma_f32_16x16x32_bf16(a, bw[1][kk], acc[m][1], 0, 0, 0);
    }

  const float b1v0 = b1[colb + colq], b1v1 = b1[colb + 16 + colq];
  #pragma unroll
  for (int m = 0; m < 5; ++m)
    #pragma unroll
    for (int r = 0; r < 4; ++r) {
      const int row = m * 16 + krow * 4 + r;
      tA[row * PADC + colb + colq]      = f2bf(silu_f(acc[m][0][r] + b1v0));
      tA[row * PADC + colb + 16 + colq] = f2bf(silu_f(acc[m][1][r] + b1v1));
    }
  __syncthreads();

  // ---- GEMM2: y = x + t @ W2 + b2 ----
  #pragma unroll
  for (int n2 = 0; n2 < 2; ++n2)
    #pragma unroll
    for (int kk = 0; kk < 4; ++kk)
      bw[n2][kk] = *(const bf16x8*)(wt2 + (size_t)(colb + n2 * 16 + colq) * CC + kk * 32 + krow * 8);

  f32x4 acc2[5][2];
  #pragma unroll
  for (int m = 0; m < 5; ++m) { acc2[m][0] = (f32x4)0.f; acc2[m][1] = (f32x4)0.f; }

  #pragma unroll
  for (int m = 0; m < 5; ++m)
    #pragma unroll
    for (int kk = 0; kk < 4; ++kk) {
      const bf16x8 a = *(const bf16x8*)(&tA[(m * 16 + colq) * PADC + kk * 32 + krow * 8]);
      acc2[m][0] = __builtin_amdgcn_mfma_f32_16x16x32_bf16(a, bw[0][kk], acc2[m][0], 0, 0, 0);
      acc2[m][1] = __builtin_amdgcn_mfma_f32_16x16x32_bf16(a, bw[1][kk], acc2[m][1], 0, 0, 0);
    }

  const float b2v0 = b2[colb + colq], b2v1 = b2[colb + 16 + colq];
  float yv[5][2][4];
  #pragma unroll
  for (int m = 0; m < 5; ++m)
    #pragma unroll
    for (int r = 0; r < 4; ++r) {
      const int row = m * 16 + krow * 4 + r;
      yv[m][0][r] = acc2[m][0][r] + b2v0 + x_in[(size_t)(node0 + row) * CC + colb + colq];
      yv[m][1][r] = acc2[m][1][r] + b2v1 + x_in[(size_t)(node0 + row) * CC + colb + 16 + colq];
    }

  // ---- LayerNorm: per-row stats across 4 waves ----
  #pragma unroll
  for (int m = 0; m < 5; ++m)
    #pragma unroll
    for (int r = 0; r < 4; ++r) {
      float s = yv[m][0][r] + yv[m][1][r];
      float s2 = yv[m][0][r] * yv[m][0][r] + yv[m][1][r] * yv[m][1][r];
      #pragma unroll
      for (int off = 1; off < 16; off <<= 1) {
        s  += __shfl_xor(s, off);
        s2 += __shfl_xor(s2, off);
      }
      if (colq == 0) {
        const int row = m * 16 + krow * 4 + r;
        red[row][wv][0] = s;
        red[row][wv][1] = s2;
      }
    }
  __syncthreads();

  const float gm0 = gamma[colb + colq], gm1 = gamma[colb + 16 + colq];
  const float bt0 = beta[colb + colq],  bt1 = beta[colb + 16 + colq];
  #pragma unroll
  for (int m = 0; m < 5; ++m)
    #pragma unroll
    for (int r = 0; r < 4; ++r) {
      const int row = m * 16 + krow * 4 + r;
      const float s  = red[row][0][0] + red[row][1][0] + red[row][2][0] + red[row][3][0];
      const float s2 = red[row][0][1] + red[row][1][1] + red[row][2][1] + red[row][3][1];
      const float mean = s * (1.f / 128.f);
      const float var = s2 * (1.f / 128.f) - mean * mean;
      const float rstd = rsqrtf(var + LN_EPS);
      float* op = x_out + (size_t)(node0 + row) * CC + colb;
      op[colq]      = (yv[m][0][r] - mean) * rstd * gm0 + bt0;
      op[16 + colq] = (yv[m][1][r] - mean) * rstd * gm1 + bt1;
    }
}

// ---------------- launch ----------------

extern "C" void kernel_launch(void* const* d_in, const int* in_sizes, int n_in,
                              void* d_out, int out_size, void* d_ws, size_t ws_size,
                              hipStream_t stream) {
  const float* x         = (const float*)d_in[0];
  const float* edge_attr = (const float*)d_in[1];
  const float* We        = (const float*)d_in[2];
  const float* be        = (const float*)d_in[3];
  const float* W1        = (const float*)d_in[4];
  const float* b1        = (const float*)d_in[5];
  const float* W2        = (const float*)d_in[6];
  const float* b2        = (const float*)d_in[7];
  const float* gamma     = (const float*)d_in[8];
  const float* beta      = (const float*)d_in[9];
  const int*   ei        = (const int*)d_in[10];
  const int*   src       = ei;        // edge_index[0]
  const int*   dst       = ei + EE;   // edge_index[1]
  float* out = (float*)d_out;

  char* ws = (char*)d_ws;
  float*          xbuf   = (float*)(ws + 0);                    // 25,600,000
  unsigned short* hbuf   = (unsigned short*)(ws + 25600000);    // 12,800,000 -> 38,400,000
  unsigned short* wt     = (unsigned short*)(ws + 38400000);    //    262,144 -> 38,662,144
  int*            counts = (int*)(ws + 38662400);               //    200,000 -> 38,862,400
  int*            rowptr = (int*)(ws + 38862592);               //    200,004 -> 39,062,596
  int*            cursor = (int*)(ws + 39062784);               //    200,000 -> 39,262,784
  int*            eidx   = (int*)(ws + 39262976);               //  2,400,000 -> 41,662,976
  int*            esrc   = (int*)(ws + 41663232);               //  2,400,000 -> 44,063,232
  unsigned short* ea     = (unsigned short*)(ws + 44063232);    // 153,600,000 -> 197,663,232
  // webf (8KB) aliases the cursor region -- cursor is dead after fill_kernel.
  unsigned short* webf   = (unsigned short*)(ws + 39062784);
  const bool use_ea = (ws_size >= 197663232ull);

  hipMemsetAsync(counts, 0, (size_t)NN * 4, stream);
  hipMemsetAsync(cursor, 0, (size_t)NN * 4, stream);
  count_kernel<<<(EE + 255) / 256, 256, 0, stream>>>(dst, counts, EE);
  scan_kernel<<<1, 1024, 0, stream>>>(counts, rowptr, NN);
  fill_kernel<<<(EE + 255) / 256, 256, 0, stream>>>(src, dst, rowptr, cursor, eidx, esrc, EE);
  wconv_kernel<<<LL * 2 * CC, 128, 0, stream>>>(W1, W2, wt);
  if (use_ea) {
    webconv_kernel<<<16, 256, 0, stream>>>(We, webf);
    ea_kernel<<<EE / 64, 256, 0, stream>>>(edge_attr, webf, be, eidx, ea);
  }

  const float* xin = x;
  float* bufs[LL] = { xbuf, out, xbuf, out };
  for (int l = 0; l < LL; ++l) {
    float* xo = bufs[l];
    if (use_ea)
      agg_kernel<0><<<NN / 2, 256, 0, stream>>>(xin, hbuf, ea, edge_attr, We, be, rowptr, eidx, esrc);
    else
      agg_kernel<1><<<NN / 2, 256, 0, stream>>>(xin, hbuf, ea, edge_attr, We, be, rowptr, eidx, esrc);
    mlp_kernel<<<NN / MTILE, 256, 0, stream>>>(
        xin, hbuf,
        wt + ((size_t)l * 2) * CC * CC, wt + ((size_t)l * 2 + 1) * CC * CC,
        b1 + (size_t)l * CC, b2 + (size_t)l * CC,
        gamma + (size_t)l * CC, beta + (size_t)l * CC, xo);
    xin = xo;
  }
}

// Round 4
// 527.194 us; speedup vs baseline: 2.2544x; 1.2838x over previous
//
#include <hip/hip_runtime.h>

#define NN 50000
#define EE 600000
#define CC 128
#define ECC 16
#define LL 4
#define LN_EPS 1e-5f
#define MTILE 80
#define PADC 136   // LDS row stride in bf16 elems: 136*2B = 17*16B -> 2-way (free) bank pattern

typedef float f32x4 __attribute__((ext_vector_type(4)));
typedef short bf16x8 __attribute__((ext_vector_type(8)));

static __device__ __forceinline__ float bf2f(unsigned short u) {
  union { unsigned int i; float f; } v; v.i = ((unsigned int)u) << 16; return v.f;
}
static __device__ __forceinline__ unsigned short f2bf(float f) {
  union { float f; unsigned int i; } v; v.f = f;
  unsigned int b = v.i + 0x7FFFu + ((v.i >> 16) & 1u);
  return (unsigned short)(b >> 16);
}
static __device__ __forceinline__ float silu_f(float v) {
  return v / (1.f + __expf(-v));
}

// ---------------- CSR build ----------------

__global__ void count_kernel(const int* __restrict__ dst, int* __restrict__ counts, int E) {
  int e = blockIdx.x * blockDim.x + threadIdx.x;
  if (e < E) atomicAdd(&counts[dst[e]], 1);
}

// --- multi-block scan: 49 blocks x 1024 ---
__global__ __launch_bounds__(1024) void scan1_kernel(const int* __restrict__ counts,
                                                     int* __restrict__ bsum, int n) {
  __shared__ int wsum[16];
  const int tid = threadIdx.x, lane = tid & 63, wv = tid >> 6;
  const int i = blockIdx.x * 1024 + tid;
  int s = (i < n) ? counts[i] : 0;
  #pragma unroll
  for (int off = 1; off < 64; off <<= 1) s += __shfl_xor(s, off);
  if (lane == 0) wsum[wv] = s;
  __syncthreads();
  if (tid == 0) {
    int t = 0;
    #pragma unroll
    for (int j = 0; j < 16; ++j) t += wsum[j];
    bsum[blockIdx.x] = t;
  }
}

__global__ void scan2_kernel(const int* __restrict__ bsum, int* __restrict__ boff, int nb) {
  const int lane = threadIdx.x;   // one wave
  int v = (lane < nb) ? bsum[lane] : 0;
  int incl = v;
  #pragma unroll
  for (int off = 1; off < 64; off <<= 1) {
    int t = __shfl_up(incl, off);
    if (lane >= off) incl += t;
  }
  if (lane < nb) boff[lane] = incl - v;
}

__global__ __launch_bounds__(1024) void scan3_kernel(const int* __restrict__ counts,
                                                     const int* __restrict__ boff,
                                                     int* __restrict__ rowptr, int n) {
  __shared__ int wsum[16];
  const int tid = threadIdx.x, lane = tid & 63, wv = tid >> 6;
  const int i = blockIdx.x * 1024 + tid;
  const int v = (i < n) ? counts[i] : 0;
  int incl = v;
  #pragma unroll
  for (int off = 1; off < 64; off <<= 1) {
    int t = __shfl_up(incl, off);
    if (lane >= off) incl += t;
  }
  if (lane == 63) wsum[wv] = incl;
  __syncthreads();
  if (wv == 0) {
    int vv = (lane < 16) ? wsum[lane] : 0;
    int vi = vv;
    #pragma unroll
    for (int off = 1; off < 16; off <<= 1) {
      int t = __shfl_up(vi, off);
      if (lane >= off) vi += t;
    }
    if (lane < 16) wsum[lane] = vi - vv;   // exclusive wave prefix
  }
  __syncthreads();
  if (i < n) rowptr[i + 1] = boff[blockIdx.x] + wsum[wv] + incl;
  if (i == 0) rowptr[0] = 0;
}

__global__ void fill_kernel(const int* __restrict__ src, const int* __restrict__ dst,
                            const int* __restrict__ rowptr, int* __restrict__ cursor,
                            int* __restrict__ eidx, int* __restrict__ esrc, int E) {
  int e = blockIdx.x * blockDim.x + threadIdx.x;
  if (e < E) {
    const int d = dst[e];
    const int pos = rowptr[d] + atomicAdd(&cursor[d], 1);
    eidx[pos] = e;
    esrc[pos] = src[e];
  }
}

// ---------------- We B-fragment prep (bf16, MFMA fragment order) ----------------
// webf[cg*512 + l*8 + j] = (k<16 ? bf16(We[k][cg*16+(l&15)]) : 0), k=(l>>4)*8+j

__global__ void webconv_kernel(const float* __restrict__ We, unsigned short* __restrict__ webf) {
  const int t = blockIdx.x * blockDim.x + threadIdx.x;
  if (t >= 8 * 64 * 8) return;
  const int j = t & 7, l = (t >> 3) & 63, cg = t >> 9;
  const int k = (l >> 4) * 8 + j, c = cg * 16 + (l & 15);
  webf[t] = (k < 16) ? f2bf(We[k * CC + c]) : (unsigned short)0;
}

// ---------------- ea precompute via MFMA (CSR order, bf16) ----------------
// Block: 256 threads / 4 waves, 64 CSR positions. Wave w: rows w*16..w*16+15.

__global__ __launch_bounds__(256) void ea_kernel(const float* __restrict__ edge_attr,
                                                 const unsigned short* __restrict__ webf,
                                                 const float* __restrict__ be,
                                                 const int* __restrict__ eidx,
                                                 unsigned short* __restrict__ ea) {
  __shared__ float er[64][20];   // pad 20: 16B-aligned float4 rows, <=2-way banks
  const int tid = threadIdx.x;
  const int lane = tid & 63, wv = tid >> 6;

  bf16x8 bw[8];
  #pragma unroll
  for (int cg = 0; cg < 8; ++cg)
    bw[cg] = *(const bf16x8*)(webf + cg * 512 + lane * 8);
  float bev[8];
  #pragma unroll
  for (int cg = 0; cg < 8; ++cg) bev[cg] = be[cg * 16 + (lane & 15)];

  const int base = blockIdx.x * 64;
  {
    const int r = tid >> 2, q = tid & 3;
    const int e = eidx[base + r];
    *(float4*)(&er[r][q * 4]) = *(const float4*)(edge_attr + (size_t)e * ECC + q * 4);
  }
  __syncthreads();

  // A-fragment: row = lane&15 (edge), k-octet = lane>>4; k>=16 -> zero pad
  const int arow = wv * 16 + (lane & 15);
  const int ko = lane >> 4;
  union { unsigned short u[8]; bf16x8 v; } afu;
  if (ko < 2) {
    #pragma unroll
    for (int j = 0; j < 8; ++j) afu.u[j] = f2bf(er[arow][ko * 8 + j]);
  } else {
    #pragma unroll
    for (int j = 0; j < 8; ++j) afu.u[j] = 0;
  }

  f32x4 acc[8];
  #pragma unroll
  for (int cg = 0; cg < 8; ++cg) {
    acc[cg] = (f32x4)0.f;
    acc[cg] = __builtin_amdgcn_mfma_f32_16x16x32_bf16(afu.v, bw[cg], acc[cg], 0, 0, 0);
  }

  // epilogue: C row = (lane>>4)*4+r (edge), col = cg*16 + (lane&15)
  const int row0 = base + wv * 16 + ko * 4;
  const int cb = lane & 15;
  #pragma unroll
  for (int cg = 0; cg < 8; ++cg)
    #pragma unroll
    for (int r = 0; r < 4; ++r) {
      const float v = acc[cg][r] + bev[cg];
      ea[(size_t)(row0 + r) * CC + cg * 16 + cb] = f2bf(silu_f(v));
    }
}

// ---------------- weight transpose+cast: wt[l][mat][c][k] = bf16(W[l][k][c]) ----------------

__global__ __launch_bounds__(128) void wconv_kernel(const float* __restrict__ W1,
                                                    const float* __restrict__ W2,
                                                    unsigned short* __restrict__ wt) {
  const int b = blockIdx.x;
  const int c = b & (CC - 1);
  const int mat = (b >> 7) & 1;
  const int l = b >> 8;
  const float* W = (mat ? W2 : W1) + (size_t)l * CC * CC;
  unsigned short* o = wt + ((size_t)l * 2 + mat) * CC * CC + (size_t)c * CC;
  const int k = threadIdx.x;
  o[k] = f2bf(W[(size_t)k * CC + c]);
}

// ---------------- aggregation (fast path): wave-per-node, 2 channels/lane ----------------
// h[n] = bf16( x[n] + sum_e relu(x[src]+ea[e]) ); ea read as packed 2xbf16 (CSR order).

__global__ __launch_bounds__(256) void agg2_kernel(const float* __restrict__ x_in,
                                                   unsigned short* __restrict__ h_out,
                                                   const unsigned int* __restrict__ ea32,
                                                   const int* __restrict__ rowptr,
                                                   const int* __restrict__ esrc) {
  const int tid = threadIdx.x;
  const int lane = tid & 63;
  const int wv = tid >> 6;
  const int n = blockIdx.x * 4 + wv;

  const int p0 = rowptr[n], p1 = rowptr[n + 1];
  float ax = 0.f, ay = 0.f;
  int p = p0;
  for (; p + 4 <= p1; p += 4) {
    const int s0 = esrc[p], s1 = esrc[p + 1], s2 = esrc[p + 2], s3 = esrc[p + 3];
    const float2 x0 = *(const float2*)(x_in + (size_t)s0 * CC + lane * 2);
    const float2 x1 = *(const float2*)(x_in + (size_t)s1 * CC + lane * 2);
    const float2 x2 = *(const float2*)(x_in + (size_t)s2 * CC + lane * 2);
    const float2 x3 = *(const float2*)(x_in + (size_t)s3 * CC + lane * 2);
    const unsigned int e0 = ea32[(size_t)p * 64 + lane];
    const unsigned int e1 = ea32[(size_t)(p + 1) * 64 + lane];
    const unsigned int e2 = ea32[(size_t)(p + 2) * 64 + lane];
    const unsigned int e3 = ea32[(size_t)(p + 3) * 64 + lane];
    ax += fmaxf(x0.x + bf2f((unsigned short)e0), 0.f)
        + fmaxf(x1.x + bf2f((unsigned short)e1), 0.f)
        + fmaxf(x2.x + bf2f((unsigned short)e2), 0.f)
        + fmaxf(x3.x + bf2f((unsigned short)e3), 0.f);
    ay += fmaxf(x0.y + bf2f((unsigned short)(e0 >> 16)), 0.f)
        + fmaxf(x1.y + bf2f((unsigned short)(e1 >> 16)), 0.f)
        + fmaxf(x2.y + bf2f((unsigned short)(e2 >> 16)), 0.f)
        + fmaxf(x3.y + bf2f((unsigned short)(e3 >> 16)), 0.f);
  }
  for (; p < p1; ++p) {
    const int s0 = esrc[p];
    const float2 x0 = *(const float2*)(x_in + (size_t)s0 * CC + lane * 2);
    const unsigned int e0 = ea32[(size_t)p * 64 + lane];
    ax += fmaxf(x0.x + bf2f((unsigned short)e0), 0.f);
    ay += fmaxf(x0.y + bf2f((unsigned short)(e0 >> 16)), 0.f);
  }
  const float2 xs = *(const float2*)(x_in + (size_t)n * CC + lane * 2);
  const unsigned int packed =
      (unsigned int)f2bf(xs.x + ax) | ((unsigned int)f2bf(xs.y + ay) << 16);
  *(unsigned int*)(h_out + (size_t)n * CC + lane * 2) = packed;
}

// ---------------- aggregation (fallback: recompute ea on the fly) ----------------

__global__ __launch_bounds__(256) void agg_fb_kernel(const float* __restrict__ x_in,
                                                     unsigned short* __restrict__ h_out,
                                                     const float* __restrict__ edge_attr,
                                                     const float* __restrict__ We,
                                                     const float* __restrict__ be,
                                                     const int* __restrict__ rowptr,
                                                     const int* __restrict__ eidx,
                                                     const int* __restrict__ esrc) {
  const int tid = threadIdx.x;
  const int c = tid & (CC - 1);
  const int g = tid >> 7;
  const int n = blockIdx.x * 2 + g;

  float wec[ECC];
  #pragma unroll
  for (int k = 0; k < ECC; ++k) wec[k] = We[k * CC + c];
  const float bev = be[c];

  const int p0 = rowptr[n], p1 = rowptr[n + 1];
  float acc = 0.f;
  for (int p = p0; p < p1; ++p) {
    const int e0 = eidx[p];
    const int s0 = esrc[p];
    const float4* ar0 = (const float4*)(edge_attr + (size_t)e0 * ECC);
    const float4 a0 = ar0[0], a1 = ar0[1], a2 = ar0[2], a3 = ar0[3];
    float v0 = bev
      + a0.x*wec[0]  + a0.y*wec[1]  + a0.z*wec[2]  + a0.w*wec[3]
      + a1.x*wec[4]  + a1.y*wec[5]  + a1.z*wec[6]  + a1.w*wec[7]
      + a2.x*wec[8]  + a2.y*wec[9]  + a2.z*wec[10] + a2.w*wec[11]
      + a3.x*wec[12] + a3.y*wec[13] + a3.z*wec[14] + a3.w*wec[15];
    acc += fmaxf(x_in[(size_t)s0 * CC + c] + silu_f(v0), 0.f);
  }
  h_out[(size_t)n * CC + c] = f2bf(x_in[(size_t)n * CC + c] + acc);
}

// ---------------- fused MLP + residual + LayerNorm (MFMA bf16) ----------------
// Block: 256 threads (4 waves), MTILE=80 nodes. Wave w owns output cols [32w, 32w+32).

__global__ __launch_bounds__(256) void mlp_kernel(const float* __restrict__ x_in,
                                                  const unsigned short* __restrict__ hbuf,
                                                  const unsigned short* __restrict__ wt1,
                                                  const unsigned short* __restrict__ wt2,
                                                  const float* __restrict__ b1,
                                                  const float* __restrict__ b2,
                                                  const float* __restrict__ gamma,
                                                  const float* __restrict__ beta,
                                                  float* __restrict__ x_out) {
  __shared__ unsigned short hA[MTILE * PADC];
  __shared__ unsigned short tA[MTILE * PADC];
  __shared__ float red[MTILE][4][2];

  const int tid = threadIdx.x;
  const int lane = tid & 63;
  const int wv = tid >> 6;
  const int node0 = blockIdx.x * MTILE;
  const int colq = lane & 15;   // col within 16-tile
  const int krow = lane >> 4;   // 0..3
  const int colb = wv * 32;

  // stage h tile (bf16, 16B per thread-chunk)
  for (int idx = tid; idx < MTILE * 16; idx += 256) {
    const int row = idx >> 4, ch = idx & 15;
    *(uint4*)(&hA[row * PADC + ch * 8]) =
        *(const uint4*)(hbuf + (size_t)(node0 + row) * CC + ch * 8);
  }
  __syncthreads();

  // ---- GEMM1: t = silu(h @ W1 + b1) ----
  bf16x8 bw[2][4];
  #pragma unroll
  for (int n2 = 0; n2 < 2; ++n2)
    #pragma unroll
    for (int kk = 0; kk < 4; ++kk)
      bw[n2][kk] = *(const bf16x8*)(wt1 + (size_t)(colb + n2 * 16 + colq) * CC + kk * 32 + krow * 8);

  f32x4 acc[5][2];
  #pragma unroll
  for (int m = 0; m < 5; ++m) { acc[m][0] = (f32x4)0.f; acc[m][1] = (f32x4)0.f; }

  #pragma unroll
  for (int m = 0; m < 5; ++m)
    #pragma unroll
    for (int kk = 0; kk < 4; ++kk) {
      const bf16x8 a = *(const bf16x8*)(&hA[(m * 16 + colq) * PADC + kk * 32 + krow * 8]);
      acc[m][0] = __builtin_amdgcn_mfma_f32_16x16x32_bf16(a, bw[0][kk], acc[m][0], 0, 0, 0);
      acc[m][1] = __builtin_amdgcn_mfma_f32_16x16x32_bf16(a, bw[1][kk], acc[m][1], 0, 0, 0);
    }

  const float b1v0 = b1[colb + colq], b1v1 = b1[colb + 16 + colq];
  #pragma unroll
  for (int m = 0; m < 5; ++m)
    #pragma unroll
    for (int r = 0; r < 4; ++r) {
      const int row = m * 16 + krow * 4 + r;
      tA[row * PADC + colb + colq]      = f2bf(silu_f(acc[m][0][r] + b1v0));
      tA[row * PADC + colb + 16 + colq] = f2bf(silu_f(acc[m][1][r] + b1v1));
    }
  __syncthreads();

  // ---- GEMM2: y = x + t @ W2 + b2 ----
  #pragma unroll
  for (int n2 = 0; n2 < 2; ++n2)
    #pragma unroll
    for (int kk = 0; kk < 4; ++kk)
      bw[n2][kk] = *(const bf16x8*)(wt2 + (size_t)(colb + n2 * 16 + colq) * CC + kk * 32 + krow * 8);

  f32x4 acc2[5][2];
  #pragma unroll
  for (int m = 0; m < 5; ++m) { acc2[m][0] = (f32x4)0.f; acc2[m][1] = (f32x4)0.f; }

  #pragma unroll
  for (int m = 0; m < 5; ++m)
    #pragma unroll
    for (int kk = 0; kk < 4; ++kk) {
      const bf16x8 a = *(const bf16x8*)(&tA[(m * 16 + colq) * PADC + kk * 32 + krow * 8]);
      acc2[m][0] = __builtin_amdgcn_mfma_f32_16x16x32_bf16(a, bw[0][kk], acc2[m][0], 0, 0, 0);
      acc2[m][1] = __builtin_amdgcn_mfma_f32_16x16x32_bf16(a, bw[1][kk], acc2[m][1], 0, 0, 0);
    }

  const float b2v0 = b2[colb + colq], b2v1 = b2[colb + 16 + colq];
  float yv[5][2][4];
  #pragma unroll
  for (int m = 0; m < 5; ++m)
    #pragma unroll
    for (int r = 0; r < 4; ++r) {
      const int row = m * 16 + krow * 4 + r;
      yv[m][0][r] = acc2[m][0][r] + b2v0 + x_in[(size_t)(node0 + row) * CC + colb + colq];
      yv[m][1][r] = acc2[m][1][r] + b2v1 + x_in[(size_t)(node0 + row) * CC + colb + 16 + colq];
    }

  // ---- LayerNorm: per-row stats across 4 waves ----
  #pragma unroll
  for (int m = 0; m < 5; ++m)
    #pragma unroll
    for (int r = 0; r < 4; ++r) {
      float s = yv[m][0][r] + yv[m][1][r];
      float s2 = yv[m][0][r] * yv[m][0][r] + yv[m][1][r] * yv[m][1][r];
      #pragma unroll
      for (int off = 1; off < 16; off <<= 1) {
        s  += __shfl_xor(s, off);
        s2 += __shfl_xor(s2, off);
      }
      if (colq == 0) {
        const int row = m * 16 + krow * 4 + r;
        red[row][wv][0] = s;
        red[row][wv][1] = s2;
      }
    }
  __syncthreads();

  const float gm0 = gamma[colb + colq], gm1 = gamma[colb + 16 + colq];
  const float bt0 = beta[colb + colq],  bt1 = beta[colb + 16 + colq];
  #pragma unroll
  for (int m = 0; m < 5; ++m)
    #pragma unroll
    for (int r = 0; r < 4; ++r) {
      const int row = m * 16 + krow * 4 + r;
      const float s  = red[row][0][0] + red[row][1][0] + red[row][2][0] + red[row][3][0];
      const float s2 = red[row][0][1] + red[row][1][1] + red[row][2][1] + red[row][3][1];
      const float mean = s * (1.f / 128.f);
      const float var = s2 * (1.f / 128.f) - mean * mean;
      const float rstd = rsqrtf(var + LN_EPS);
      float* op = x_out + (size_t)(node0 + row) * CC + colb;
      op[colq]      = (yv[m][0][r] - mean) * rstd * gm0 + bt0;
      op[16 + colq] = (yv[m][1][r] - mean) * rstd * gm1 + bt1;
    }
}

// ---------------- launch ----------------

extern "C" void kernel_launch(void* const* d_in, const int* in_sizes, int n_in,
                              void* d_out, int out_size, void* d_ws, size_t ws_size,
                              hipStream_t stream) {
  const float* x         = (const float*)d_in[0];
  const float* edge_attr = (const float*)d_in[1];
  const float* We        = (const float*)d_in[2];
  const float* be        = (const float*)d_in[3];
  const float* W1        = (const float*)d_in[4];
  const float* b1        = (const float*)d_in[5];
  const float* W2        = (const float*)d_in[6];
  const float* b2        = (const float*)d_in[7];
  const float* gamma     = (const float*)d_in[8];
  const float* beta      = (const float*)d_in[9];
  const int*   ei        = (const int*)d_in[10];
  const int*   src       = ei;        // edge_index[0]
  const int*   dst       = ei + EE;   // edge_index[1]
  float* out = (float*)d_out;

  char* ws = (char*)d_ws;
  float*          xbuf   = (float*)(ws + 0);                    // 25,600,000
  unsigned short* hbuf   = (unsigned short*)(ws + 25600000);    // 12,800,000 -> 38,400,000
  unsigned short* wt     = (unsigned short*)(ws + 38400000);    //    262,144 -> 38,662,144
  int*            counts = (int*)(ws + 38662400);               //    200,000 -> 38,862,400
  int*            rowptr = (int*)(ws + 38862592);               //    200,004 -> 39,062,596
  int*            cursor = (int*)(ws + 39062784);               //    200,000 -> 39,262,784
  int*            eidx   = (int*)(ws + 39262976);               //  2,400,000 -> 41,662,976
  int*            esrc   = (int*)(ws + 41663232);               //  2,400,000 -> 44,063,232
  unsigned short* ea     = (unsigned short*)(ws + 44063232);    // 153,600,000 -> 197,663,232
  // webf (8KB) aliases the cursor region -- cursor is dead after fill_kernel.
  unsigned short* webf   = (unsigned short*)(ws + 39062784);
  // scan scratch aliases eidx (dead until fill_kernel, which runs after the scan).
  int*            bsum   = (int*)(ws + 39262976);
  int*            boff   = (int*)(ws + 39262976 + 256);
  const bool use_ea = (ws_size >= 197663232ull);
  const int NB = (NN + 1023) / 1024;   // 49

  hipMemsetAsync(counts, 0, (size_t)NN * 4, stream);
  hipMemsetAsync(cursor, 0, (size_t)NN * 4, stream);
  count_kernel<<<(EE + 255) / 256, 256, 0, stream>>>(dst, counts, EE);
  scan1_kernel<<<NB, 1024, 0, stream>>>(counts, bsum, NN);
  scan2_kernel<<<1, 64, 0, stream>>>(bsum, boff, NB);
  scan3_kernel<<<NB, 1024, 0, stream>>>(counts, boff, rowptr, NN);
  fill_kernel<<<(EE + 255) / 256, 256, 0, stream>>>(src, dst, rowptr, cursor, eidx, esrc, EE);
  wconv_kernel<<<LL * 2 * CC, 128, 0, stream>>>(W1, W2, wt);
  if (use_ea) {
    webconv_kernel<<<16, 256, 0, stream>>>(We, webf);
    ea_kernel<<<EE / 64, 256, 0, stream>>>(edge_attr, webf, be, eidx, ea);
  }

  const float* xin = x;
  float* bufs[LL] = { xbuf, out, xbuf, out };
  for (int l = 0; l < LL; ++l) {
    float* xo = bufs[l];
    if (use_ea)
      agg2_kernel<<<NN / 4, 256, 0, stream>>>(xin, hbuf, (const unsigned int*)ea, rowptr, esrc);
    else
      agg_fb_kernel<<<NN / 2, 256, 0, stream>>>(xin, hbuf, edge_attr, We, be, rowptr, eidx, esrc);
    mlp_kernel<<<NN / MTILE, 256, 0, stream>>>(
        xin, hbuf,
        wt + ((size_t)l * 2) * CC * CC, wt + ((size_t)l * 2 + 1) * CC * CC,
        b1 + (size_t)l * CC, b2 + (size_t)l * CC,
        gamma + (size_t)l * CC, beta + (size_t)l * CC, xo);
    xin = xo;
  }
}

// Round 5
// 489.529 us; speedup vs baseline: 2.4279x; 1.0769x over previous
//
#include <hip/hip_runtime.h>

#define NN 50000
#define EE 600000
#define CC 128
#define ECC 16
#define LL 4
#define LN_EPS 1e-5f
#define MTILE 80
#define PADC 136   // LDS row stride in bf16 elems for hA/tA
#define YSTR 132   // f32 stride for yS overlay (2-way-free banks)

typedef float f32x4 __attribute__((ext_vector_type(4)));
typedef short bf16x8 __attribute__((ext_vector_type(8)));

static __device__ __forceinline__ float bf2f(unsigned short u) {
  union { unsigned int i; float f; } v; v.i = ((unsigned int)u) << 16; return v.f;
}
static __device__ __forceinline__ unsigned short f2bf(float f) {
  union { float f; unsigned int i; } v; v.f = f;
  unsigned int b = v.i + 0x7FFFu + ((v.i >> 16) & 1u);
  return (unsigned short)(b >> 16);
}
static __device__ __forceinline__ float silu_f(float v) {
  return v / (1.f + __expf(-v));
}

// ---------------- CSR build ----------------

__global__ void count_kernel(const int* __restrict__ dst, int* __restrict__ counts, int E) {
  int e = blockIdx.x * blockDim.x + threadIdx.x;
  if (e < E) atomicAdd(&counts[dst[e]], 1);
}

// --- multi-block scan: 49 blocks x 1024 ---
__global__ __launch_bounds__(1024) void scan1_kernel(const int* __restrict__ counts,
                                                     int* __restrict__ bsum, int n) {
  __shared__ int wsum[16];
  const int tid = threadIdx.x, lane = tid & 63, wv = tid >> 6;
  const int i = blockIdx.x * 1024 + tid;
  int s = (i < n) ? counts[i] : 0;
  #pragma unroll
  for (int off = 1; off < 64; off <<= 1) s += __shfl_xor(s, off);
  if (lane == 0) wsum[wv] = s;
  __syncthreads();
  if (tid == 0) {
    int t = 0;
    #pragma unroll
    for (int j = 0; j < 16; ++j) t += wsum[j];
    bsum[blockIdx.x] = t;
  }
}

__global__ void scan2_kernel(const int* __restrict__ bsum, int* __restrict__ boff, int nb) {
  const int lane = threadIdx.x;   // one wave
  int v = (lane < nb) ? bsum[lane] : 0;
  int incl = v;
  #pragma unroll
  for (int off = 1; off < 64; off <<= 1) {
    int t = __shfl_up(incl, off);
    if (lane >= off) incl += t;
  }
  if (lane < nb) boff[lane] = incl - v;
}

__global__ __launch_bounds__(1024) void scan3_kernel(const int* __restrict__ counts,
                                                     const int* __restrict__ boff,
                                                     int* __restrict__ rowptr, int n) {
  __shared__ int wsum[16];
  const int tid = threadIdx.x, lane = tid & 63, wv = tid >> 6;
  const int i = blockIdx.x * 1024 + tid;
  const int v = (i < n) ? counts[i] : 0;
  int incl = v;
  #pragma unroll
  for (int off = 1; off < 64; off <<= 1) {
    int t = __shfl_up(incl, off);
    if (lane >= off) incl += t;
  }
  if (lane == 63) wsum[wv] = incl;
  __syncthreads();
  if (wv == 0) {
    int vv = (lane < 16) ? wsum[lane] : 0;
    int vi = vv;
    #pragma unroll
    for (int off = 1; off < 16; off <<= 1) {
      int t = __shfl_up(vi, off);
      if (lane >= off) vi += t;
    }
    if (lane < 16) wsum[lane] = vi - vv;   // exclusive wave prefix
  }
  __syncthreads();
  if (i < n) rowptr[i + 1] = boff[blockIdx.x] + wsum[wv] + incl;
  if (i == 0) rowptr[0] = 0;
}

__global__ void fill_kernel(const int* __restrict__ src, const int* __restrict__ dst,
                            const int* __restrict__ rowptr, int* __restrict__ cursor,
                            int* __restrict__ eidx, int* __restrict__ esrc, int E) {
  int e = blockIdx.x * blockDim.x + threadIdx.x;
  if (e < E) {
    const int d = dst[e];
    const int pos = rowptr[d] + atomicAdd(&cursor[d], 1);
    eidx[pos] = e;
    esrc[pos] = src[e];
  }
}

// ---------------- We B-fragment prep (bf16, MFMA fragment order) ----------------

__global__ void webconv_kernel(const float* __restrict__ We, unsigned short* __restrict__ webf) {
  const int t = blockIdx.x * blockDim.x + threadIdx.x;
  if (t >= 8 * 64 * 8) return;
  const int j = t & 7, l = (t >> 3) & 63, cg = t >> 9;
  const int k = (l >> 4) * 8 + j, c = cg * 16 + (l & 15);
  webf[t] = (k < 16) ? f2bf(We[k * CC + c]) : (unsigned short)0;
}

// ---------------- ea precompute via MFMA (CSR order, bf16, coalesced stores) ----------------
// Block: 256 threads / 4 waves, 64 CSR positions. Wave w: rows w*16..w*16+15.

__global__ __launch_bounds__(256) void ea_kernel(const float* __restrict__ edge_attr,
                                                 const unsigned short* __restrict__ webf,
                                                 const float* __restrict__ be,
                                                 const int* __restrict__ eidx,
                                                 unsigned short* __restrict__ ea) {
  __shared__ float er[64][20];           // pad 20: 16B-aligned float4 rows
  __shared__ unsigned short eaT[64 * 132]; // repack tile, stride 132 shorts (264B)
  const int tid = threadIdx.x;
  const int lane = tid & 63, wv = tid >> 6;

  bf16x8 bw[8];
  #pragma unroll
  for (int cg = 0; cg < 8; ++cg)
    bw[cg] = *(const bf16x8*)(webf + cg * 512 + lane * 8);
  float bev[8];
  #pragma unroll
  for (int cg = 0; cg < 8; ++cg) bev[cg] = be[cg * 16 + (lane & 15)];

  const int base = blockIdx.x * 64;
  {
    const int r = tid >> 2, q = tid & 3;
    const int e = eidx[base + r];
    *(float4*)(&er[r][q * 4]) = *(const float4*)(edge_attr + (size_t)e * ECC + q * 4);
  }
  __syncthreads();

  // A-fragment: row = lane&15 (edge), k-octet = lane>>4; k>=16 -> zero pad
  const int arow = wv * 16 + (lane & 15);
  const int ko = lane >> 4;
  union { unsigned short u[8]; bf16x8 v; } afu;
  if (ko < 2) {
    #pragma unroll
    for (int j = 0; j < 8; ++j) afu.u[j] = f2bf(er[arow][ko * 8 + j]);
  } else {
    #pragma unroll
    for (int j = 0; j < 8; ++j) afu.u[j] = 0;
  }

  f32x4 acc[8];
  #pragma unroll
  for (int cg = 0; cg < 8; ++cg) {
    acc[cg] = (f32x4)0.f;
    acc[cg] = __builtin_amdgcn_mfma_f32_16x16x32_bf16(afu.v, bw[cg], acc[cg], 0, 0, 0);
  }

  // epilogue: silu+pack into LDS (C row = wv*16 + ko*4 + r, col = cg*16 + cb)
  const int rl0 = wv * 16 + ko * 4;
  const int cb = lane & 15;
  #pragma unroll
  for (int cg = 0; cg < 8; ++cg)
    #pragma unroll
    for (int r = 0; r < 4; ++r) {
      const float v = acc[cg][r] + bev[cg];
      eaT[(rl0 + r) * 132 + cg * 16 + cb] = f2bf(silu_f(v));
    }
  __syncthreads();

  // coalesced store: 64 rows x 256B; unit u -> global byte base*256 + u*16
  uint4* eg = (uint4*)(ea + (size_t)base * CC);
  #pragma unroll
  for (int k = 0; k < 4; ++k) {
    const int u = tid + k * 256;
    const int row = u >> 4, ch = u & 15;
    eg[u] = *(const uint4*)(&eaT[row * 132 + ch * 8]);
  }
}

// ---------------- weight transpose+cast: wt[l][mat][c][k] = bf16(W[l][k][c]) ----------------

__global__ __launch_bounds__(128) void wconv_kernel(const float* __restrict__ W1,
                                                    const float* __restrict__ W2,
                                                    unsigned short* __restrict__ wt) {
  const int b = blockIdx.x;
  const int c = b & (CC - 1);
  const int mat = (b >> 7) & 1;
  const int l = b >> 8;
  const float* W = (mat ? W2 : W1) + (size_t)l * CC * CC;
  unsigned short* o = wt + ((size_t)l * 2 + mat) * CC * CC + (size_t)c * CC;
  const int k = threadIdx.x;
  o[k] = f2bf(W[(size_t)k * CC + c]);
}

// ---------------- aggregation (fast path): wave-per-node, 2 channels/lane ----------------

__global__ __launch_bounds__(256) void agg2_kernel(const float* __restrict__ x_in,
                                                   unsigned short* __restrict__ h_out,
                                                   const unsigned int* __restrict__ ea32,
                                                   const int* __restrict__ rowptr,
                                                   const int* __restrict__ esrc) {
  const int tid = threadIdx.x;
  const int lane = tid & 63;
  const int wv = tid >> 6;
  const int n = blockIdx.x * 4 + wv;

  const int p0 = rowptr[n], p1 = rowptr[n + 1];
  float ax = 0.f, ay = 0.f;
  int p = p0;
  for (; p + 4 <= p1; p += 4) {
    const int s0 = esrc[p], s1 = esrc[p + 1], s2 = esrc[p + 2], s3 = esrc[p + 3];
    const float2 x0 = *(const float2*)(x_in + (size_t)s0 * CC + lane * 2);
    const float2 x1 = *(const float2*)(x_in + (size_t)s1 * CC + lane * 2);
    const float2 x2 = *(const float2*)(x_in + (size_t)s2 * CC + lane * 2);
    const float2 x3 = *(const float2*)(x_in + (size_t)s3 * CC + lane * 2);
    const unsigned int e0 = ea32[(size_t)p * 64 + lane];
    const unsigned int e1 = ea32[(size_t)(p + 1) * 64 + lane];
    const unsigned int e2 = ea32[(size_t)(p + 2) * 64 + lane];
    const unsigned int e3 = ea32[(size_t)(p + 3) * 64 + lane];
    ax += fmaxf(x0.x + bf2f((unsigned short)e0), 0.f)
        + fmaxf(x1.x + bf2f((unsigned short)e1), 0.f)
        + fmaxf(x2.x + bf2f((unsigned short)e2), 0.f)
        + fmaxf(x3.x + bf2f((unsigned short)e3), 0.f);
    ay += fmaxf(x0.y + bf2f((unsigned short)(e0 >> 16)), 0.f)
        + fmaxf(x1.y + bf2f((unsigned short)(e1 >> 16)), 0.f)
        + fmaxf(x2.y + bf2f((unsigned short)(e2 >> 16)), 0.f)
        + fmaxf(x3.y + bf2f((unsigned short)(e3 >> 16)), 0.f);
  }
  for (; p < p1; ++p) {
    const int s0 = esrc[p];
    const float2 x0 = *(const float2*)(x_in + (size_t)s0 * CC + lane * 2);
    const unsigned int e0 = ea32[(size_t)p * 64 + lane];
    ax += fmaxf(x0.x + bf2f((unsigned short)e0), 0.f);
    ay += fmaxf(x0.y + bf2f((unsigned short)(e0 >> 16)), 0.f);
  }
  const float2 xs = *(const float2*)(x_in + (size_t)n * CC + lane * 2);
  const unsigned int packed =
      (unsigned int)f2bf(xs.x + ax) | ((unsigned int)f2bf(xs.y + ay) << 16);
  *(unsigned int*)(h_out + (size_t)n * CC + lane * 2) = packed;
}

// ---------------- aggregation (fallback: recompute ea on the fly) ----------------

__global__ __launch_bounds__(256) void agg_fb_kernel(const float* __restrict__ x_in,
                                                     unsigned short* __restrict__ h_out,
                                                     const float* __restrict__ edge_attr,
                                                     const float* __restrict__ We,
                                                     const float* __restrict__ be,
                                                     const int* __restrict__ rowptr,
                                                     const int* __restrict__ eidx,
                                                     const int* __restrict__ esrc) {
  const int tid = threadIdx.x;
  const int c = tid & (CC - 1);
  const int g = tid >> 7;
  const int n = blockIdx.x * 2 + g;

  float wec[ECC];
  #pragma unroll
  for (int k = 0; k < ECC; ++k) wec[k] = We[k * CC + c];
  const float bev = be[c];

  const int p0 = rowptr[n], p1 = rowptr[n + 1];
  float acc = 0.f;
  for (int p = p0; p < p1; ++p) {
    const int e0 = eidx[p];
    const int s0 = esrc[p];
    const float4* ar0 = (const float4*)(edge_attr + (size_t)e0 * ECC);
    const float4 a0 = ar0[0], a1 = ar0[1], a2 = ar0[2], a3 = ar0[3];
    float v0 = bev
      + a0.x*wec[0]  + a0.y*wec[1]  + a0.z*wec[2]  + a0.w*wec[3]
      + a1.x*wec[4]  + a1.y*wec[5]  + a1.z*wec[6]  + a1.w*wec[7]
      + a2.x*wec[8]  + a2.y*wec[9]  + a2.z*wec[10] + a2.w*wec[11]
      + a3.x*wec[12] + a3.y*wec[13] + a3.z*wec[14] + a3.w*wec[15];
    acc += fmaxf(x_in[(size_t)s0 * CC + c] + silu_f(v0), 0.f);
  }
  h_out[(size_t)n * CC + c] = f2bf(x_in[(size_t)n * CC + c] + acc);
}

// ---------------- fused MLP + residual + LayerNorm (MFMA bf16) ----------------
// Block: 256 threads (4 waves), MTILE=80 nodes. Wave w owns output cols [32w, 32w+32).
// Epilogue: LN result staged f32 in LDS (overlaying hA+tA) then coalesced float4 stores.

__global__ __launch_bounds__(256) void mlp_kernel(const float* __restrict__ x_in,
                                                  const unsigned short* __restrict__ hbuf,
                                                  const unsigned short* __restrict__ wt1,
                                                  const unsigned short* __restrict__ wt2,
                                                  const float* __restrict__ b1,
                                                  const float* __restrict__ b2,
                                                  const float* __restrict__ gamma,
                                                  const float* __restrict__ beta,
                                                  float* __restrict__ x_out) {
  __shared__ __align__(16) char smem[MTILE * PADC * 2 * 2];  // 43,520 B
  unsigned short* hA = (unsigned short*)smem;                 // [MTILE][PADC]
  unsigned short* tA = (unsigned short*)(smem + MTILE * PADC * 2);
  float* yS = (float*)smem;                                   // [80][YSTR] overlay (42,240 B)
  __shared__ float red[MTILE][4][2];

  const int tid = threadIdx.x;
  const int lane = tid & 63;
  const int wv = tid >> 6;
  const int node0 = blockIdx.x * MTILE;
  const int colq = lane & 15;   // col within 16-tile
  const int krow = lane >> 4;   // 0..3
  const int colb = wv * 32;

  // stage h tile (bf16, 16B per thread-chunk)
  for (int idx = tid; idx < MTILE * 16; idx += 256) {
    const int row = idx >> 4, ch = idx & 15;
    *(uint4*)(&hA[row * PADC + ch * 8]) =
        *(const uint4*)(hbuf + (size_t)(node0 + row) * CC + ch * 8);
  }
  __syncthreads();

  // ---- GEMM1: t = silu(h @ W1 + b1) ----
  bf16x8 bw[2][4];
  #pragma unroll
  for (int n2 = 0; n2 < 2; ++n2)
    #pragma unroll
    for (int kk = 0; kk < 4; ++kk)
      bw[n2][kk] = *(const bf16x8*)(wt1 + (size_t)(colb + n2 * 16 + colq) * CC + kk * 32 + krow * 8);

  f32x4 acc[5][2];
  #pragma unroll
  for (int m = 0; m < 5; ++m) { acc[m][0] = (f32x4)0.f; acc[m][1] = (f32x4)0.f; }

  #pragma unroll
  for (int m = 0; m < 5; ++m)
    #pragma unroll
    for (int kk = 0; kk < 4; ++kk) {
      const bf16x8 a = *(const bf16x8*)(&hA[(m * 16 + colq) * PADC + kk * 32 + krow * 8]);
      acc[m][0] = __builtin_amdgcn_mfma_f32_16x16x32_bf16(a, bw[0][kk], acc[m][0], 0, 0, 0);
      acc[m][1] = __builtin_amdgcn_mfma_f32_16x16x32_bf16(a, bw[1][kk], acc[m][1], 0, 0, 0);
    }

  const float b1v0 = b1[colb + colq], b1v1 = b1[colb + 16 + colq];
  #pragma unroll
  for (int m = 0; m < 5; ++m)
    #pragma unroll
    for (int r = 0; r < 4; ++r) {
      const int row = m * 16 + krow * 4 + r;
      tA[row * PADC + colb + colq]      = f2bf(silu_f(acc[m][0][r] + b1v0));
      tA[row * PADC + colb + 16 + colq] = f2bf(silu_f(acc[m][1][r] + b1v1));
    }
  __syncthreads();

  // ---- GEMM2: y = x + t @ W2 + b2 ----
  #pragma unroll
  for (int n2 = 0; n2 < 2; ++n2)
    #pragma unroll
    for (int kk = 0; kk < 4; ++kk)
      bw[n2][kk] = *(const bf16x8*)(wt2 + (size_t)(colb + n2 * 16 + colq) * CC + kk * 32 + krow * 8);

  f32x4 acc2[5][2];
  #pragma unroll
  for (int m = 0; m < 5; ++m) { acc2[m][0] = (f32x4)0.f; acc2[m][1] = (f32x4)0.f; }

  #pragma unroll
  for (int m = 0; m < 5; ++m)
    #pragma unroll
    for (int kk = 0; kk < 4; ++kk) {
      const bf16x8 a = *(const bf16x8*)(&tA[(m * 16 + colq) * PADC + kk * 32 + krow * 8]);
      acc2[m][0] = __builtin_amdgcn_mfma_f32_16x16x32_bf16(a, bw[0][kk], acc2[m][0], 0, 0, 0);
      acc2[m][1] = __builtin_amdgcn_mfma_f32_16x16x32_bf16(a, bw[1][kk], acc2[m][1], 0, 0, 0);
    }

  const float b2v0 = b2[colb + colq], b2v1 = b2[colb + 16 + colq];
  float yv[5][2][4];
  #pragma unroll
  for (int m = 0; m < 5; ++m)
    #pragma unroll
    for (int r = 0; r < 4; ++r) {
      const int row = m * 16 + krow * 4 + r;
      yv[m][0][r] = acc2[m][0][r] + b2v0 + x_in[(size_t)(node0 + row) * CC + colb + colq];
      yv[m][1][r] = acc2[m][1][r] + b2v1 + x_in[(size_t)(node0 + row) * CC + colb + 16 + colq];
    }

  // ---- LayerNorm: per-row stats across 4 waves ----
  #pragma unroll
  for (int m = 0; m < 5; ++m)
    #pragma unroll
    for (int r = 0; r < 4; ++r) {
      float s = yv[m][0][r] + yv[m][1][r];
      float s2 = yv[m][0][r] * yv[m][0][r] + yv[m][1][r] * yv[m][1][r];
      #pragma unroll
      for (int off = 1; off < 16; off <<= 1) {
        s  += __shfl_xor(s, off);
        s2 += __shfl_xor(s2, off);
      }
      if (colq == 0) {
        const int row = m * 16 + krow * 4 + r;
        red[row][wv][0] = s;
        red[row][wv][1] = s2;
      }
    }
  __syncthreads();   // red ready; also orders all tA reads before yS overlay writes

  const float gm0 = gamma[colb + colq], gm1 = gamma[colb + 16 + colq];
  const float bt0 = beta[colb + colq],  bt1 = beta[colb + 16 + colq];
  #pragma unroll
  for (int m = 0; m < 5; ++m)
    #pragma unroll
    for (int r = 0; r < 4; ++r) {
      const int row = m * 16 + krow * 4 + r;
      const float s  = red[row][0][0] + red[row][1][0] + red[row][2][0] + red[row][3][0];
      const float s2 = red[row][0][1] + red[row][1][1] + red[row][2][1] + red[row][3][1];
      const float mean = s * (1.f / 128.f);
      const float var = s2 * (1.f / 128.f) - mean * mean;
      const float rstd = rsqrtf(var + LN_EPS);
      yS[row * YSTR + colb + colq]      = (yv[m][0][r] - mean) * rstd * gm0 + bt0;
      yS[row * YSTR + colb + 16 + colq] = (yv[m][1][r] - mean) * rstd * gm1 + bt1;
    }
  __syncthreads();

  // coalesced store: 80 rows x 512B; unit u -> global byte node0*512 + u*16
  float* og = x_out + (size_t)node0 * CC;
  #pragma unroll
  for (int k = 0; k < 10; ++k) {
    const int u = tid + k * 256;        // 2560 units of 16B
    const int row = u >> 5, q = u & 31;
    *(float4*)(og + u * 4) = *(const float4*)(&yS[row * YSTR + q * 4]);
  }
}

// ---------------- launch ----------------

extern "C" void kernel_launch(void* const* d_in, const int* in_sizes, int n_in,
                              void* d_out, int out_size, void* d_ws, size_t ws_size,
                              hipStream_t stream) {
  const float* x         = (const float*)d_in[0];
  const float* edge_attr = (const float*)d_in[1];
  const float* We        = (const float*)d_in[2];
  const float* be        = (const float*)d_in[3];
  const float* W1        = (const float*)d_in[4];
  const float* b1        = (const float*)d_in[5];
  const float* W2        = (const float*)d_in[6];
  const float* b2        = (const float*)d_in[7];
  const float* gamma     = (const float*)d_in[8];
  const float* beta      = (const float*)d_in[9];
  const int*   ei        = (const int*)d_in[10];
  const int*   src       = ei;        // edge_index[0]
  const int*   dst       = ei + EE;   // edge_index[1]
  float* out = (float*)d_out;

  char* ws = (char*)d_ws;
  float*          xbuf   = (float*)(ws + 0);                    // 25,600,000
  unsigned short* hbuf   = (unsigned short*)(ws + 25600000);    // 12,800,000 -> 38,400,000
  unsigned short* wt     = (unsigned short*)(ws + 38400000);    //    262,144 -> 38,662,144
  int*            counts = (int*)(ws + 38662400);               //    200,000 -> 38,862,400
  int*            rowptr = (int*)(ws + 38862592);               //    200,004 -> 39,062,596
  int*            cursor = (int*)(ws + 39062784);               //    200,000 -> 39,262,784
  int*            eidx   = (int*)(ws + 39262976);               //  2,400,000 -> 41,662,976
  int*            esrc   = (int*)(ws + 41663232);               //  2,400,000 -> 44,063,232
  unsigned short* ea     = (unsigned short*)(ws + 44063232);    // 153,600,000 -> 197,663,232
  // webf (8KB) aliases the cursor region -- cursor is dead after fill_kernel.
  unsigned short* webf   = (unsigned short*)(ws + 39062784);
  // scan scratch aliases eidx (dead until fill_kernel, which runs after the scan).
  int*            bsum   = (int*)(ws + 39262976);
  int*            boff   = (int*)(ws + 39262976 + 256);
  const bool use_ea = (ws_size >= 197663232ull);
  const int NB = (NN + 1023) / 1024;   // 49

  hipMemsetAsync(counts, 0, (size_t)NN * 4, stream);
  hipMemsetAsync(cursor, 0, (size_t)NN * 4, stream);
  count_kernel<<<(EE + 255) / 256, 256, 0, stream>>>(dst, counts, EE);
  scan1_kernel<<<NB, 1024, 0, stream>>>(counts, bsum, NN);
  scan2_kernel<<<1, 64, 0, stream>>>(bsum, boff, NB);
  scan3_kernel<<<NB, 1024, 0, stream>>>(counts, boff, rowptr, NN);
  fill_kernel<<<(EE + 255) / 256, 256, 0, stream>>>(src, dst, rowptr, cursor, eidx, esrc, EE);
  wconv_kernel<<<LL * 2 * CC, 128, 0, stream>>>(W1, W2, wt);
  if (use_ea) {
    webconv_kernel<<<16, 256, 0, stream>>>(We, webf);
    ea_kernel<<<EE / 64, 256, 0, stream>>>(edge_attr, webf, be, eidx, ea);
  }

  const float* xin = x;
  float* bufs[LL] = { xbuf, out, xbuf, out };
  for (int l = 0; l < LL; ++l) {
    float* xo = bufs[l];
    if (use_ea)
      agg2_kernel<<<NN / 4, 256, 0, stream>>>(xin, hbuf, (const unsigned int*)ea, rowptr, esrc);
    else
      agg_fb_kernel<<<NN / 2, 256, 0, stream>>>(xin, hbuf, edge_attr, We, be, rowptr, eidx, esrc);
    mlp_kernel<<<NN / MTILE, 256, 0, stream>>>(
        xin, hbuf,
        wt + ((size_t)l * 2) * CC * CC, wt + ((size_t)l * 2 + 1) * CC * CC,
        b1 + (size_t)l * CC, b2 + (size_t)l * CC,
        gamma + (size_t)l * CC, beta + (size_t)l * CC, xo);
    xin = xo;
  }
}